// Round 2
// baseline (165.958 us; speedup 1.0000x reference)
//
#include <hip/hip_runtime.h>
#include <hip/hip_bf16.h>
#include <stdint.h>

// ---------------------------------------------------------------------------
// SupervisedInfoNCELoss, N=8192, D=128, TAF=0.05
// loss = mean_i [ 20 + ln(sum_j exp(logit_ij - 20)) - diag_i ]
// logit_ij = zn_i . bn_j / TAF,  bn = [normalize(z_p); normalize(z_n)]
// Fixed max = 20 (cos sim <= 1) -> no online max needed.
// ---------------------------------------------------------------------------

#define TAF_F 0.05f
constexpr float LOG2E  = 1.4426950408889634f;
constexpr float SCALE  = LOG2E / TAF_F;     // logit->exp2 scale on raw dot
constexpr float OFFSET = -20.0f * LOG2E;    // subtract fixed max 20

constexpr int N_ROWS     = 8192;
constexpr int D_DIM      = 128;
constexpr int TWO_N      = 16384;
constexpr int NJ         = 32;              // column chunks (gridDim.y)
constexpr int JCHUNK     = TWO_N / NJ;      // 512 columns per block
constexpr int BN_TILE    = 64;              // j-tile staged in LDS
constexpr int NT         = JCHUNK / BN_TILE;// 8 tiles per block
constexpr int BLOCK_ROWS = 256;             // rows per block (4 waves x 64)
constexpr int WAVE_ROWS  = 64;              // rows per wave (4 strips of 16)
constexpr int TILE_BYTES = BN_TILE * D_DIM * 2;  // 16 KiB

typedef __bf16 bf16x8 __attribute__((ext_vector_type(8)));
typedef __bf16 bf16x2 __attribute__((ext_vector_type(2)));
typedef float  f32x4  __attribute__((ext_vector_type(4)));

#if __has_builtin(__builtin_amdgcn_exp2f)
#define EXP2(x) __builtin_amdgcn_exp2f(x)
#else
#define EXP2(x) exp2f(x)
#endif

// ---------------------------------------------------------------------------
// Kernel 1: per-row normalize -> bf16, plus exact f32 diagonal logit.
// One wave per row (lane holds 2 elems); 4 rows per 256-thread block.
// grid = 2048 blocks. No LDS, no __syncthreads.
// ---------------------------------------------------------------------------
__global__ void normalize_diag_kernel(const float* __restrict__ z,
                                      const float* __restrict__ zp,
                                      const float* __restrict__ znm,
                                      __bf16* __restrict__ znb,
                                      __bf16* __restrict__ bnb,
                                      float* __restrict__ diag) {
    const int wv   = threadIdx.x >> 6;
    const int lane = threadIdx.x & 63;
    const int i    = blockIdx.x * 4 + wv;

    const float2 vz = *reinterpret_cast<const float2*>(z   + (size_t)i * D_DIM + lane * 2);
    const float2 vp = *reinterpret_cast<const float2*>(zp  + (size_t)i * D_DIM + lane * 2);
    const float2 vn = *reinterpret_cast<const float2*>(znm + (size_t)i * D_DIM + lane * 2);

    float sz  = vz.x * vz.x + vz.y * vz.y;
    float sp  = vp.x * vp.x + vp.y * vp.y;
    float sn  = vn.x * vn.x + vn.y * vn.y;
    float szp = vz.x * vp.x + vz.y * vp.y;
#pragma unroll
    for (int o = 32; o >= 1; o >>= 1) {
        sz  += __shfl_xor(sz, o);
        sp  += __shfl_xor(sp, o);
        sn  += __shfl_xor(sn, o);
        szp += __shfl_xor(szp, o);
    }
    const float rz = 1.0f / fmaxf(sqrtf(sz), 1e-8f);
    const float rp = 1.0f / fmaxf(sqrtf(sp), 1e-8f);
    const float rn = 1.0f / fmaxf(sqrtf(sn), 1e-8f);

    bf16x2 oz = { (__bf16)(vz.x * rz), (__bf16)(vz.y * rz) };
    bf16x2 op = { (__bf16)(vp.x * rp), (__bf16)(vp.y * rp) };
    bf16x2 on = { (__bf16)(vn.x * rn), (__bf16)(vn.y * rn) };
    *reinterpret_cast<bf16x2*>(znb + (size_t)i * D_DIM + lane * 2)            = oz;
    *reinterpret_cast<bf16x2*>(bnb + (size_t)i * D_DIM + lane * 2)            = op;
    *reinterpret_cast<bf16x2*>(bnb + (size_t)(N_ROWS + i) * D_DIM + lane * 2) = on;
    if (lane == 0) diag[i] = szp * rz * rp * (1.0f / TAF_F);
}

// ---------------------------------------------------------------------------
// Kernel 2: fused GEMM + partial sum-of-exp. Double-buffered LDS, async
// stage split: barrier -> issue next-tile loads -> compute cur -> write next.
// grid = (N/256, NJ=32) = 1024 blocks -> 4 blocks/CU.
// mfma_f32_16x16x32_bf16: C row = (lane>>4)*4+reg, col = lane&15 (m89).
// ---------------------------------------------------------------------------
__global__ __launch_bounds__(256, 4) void partial_lse_kernel(
        const __bf16* __restrict__ znb,
        const __bf16* __restrict__ bnb,
        float* __restrict__ partial) {
    __shared__ __align__(16) unsigned char lds[TILE_BYTES * 2];  // 32 KiB

    const int tid  = threadIdx.x;
    const int lane = tid & 63;
    const int wv   = tid >> 6;
    const int l15  = lane & 15;
    const int l4   = lane >> 4;
    const int rowBase = blockIdx.x * BLOCK_ROWS + wv * WAVE_ROWS;
    const int jBase   = blockIdx.y * JCHUNK;

    // A fragments for 4 row-strips x 4 K-steps (held in VGPRs whole kernel)
    bf16x8 a[4][4];
#pragma unroll
    for (int s = 0; s < 4; ++s)
#pragma unroll
        for (int kk = 0; kk < 4; ++kk) {
            const __bf16* p = znb + (size_t)(rowBase + s * 16 + l15) * D_DIM + kk * 32 + l4 * 8;
            a[s][kk] = *reinterpret_cast<const bf16x8*>(p);
        }

    float sums[4][4];
#pragma unroll
    for (int s = 0; s < 4; ++s)
#pragma unroll
        for (int e = 0; e < 4; ++e) sums[s][e] = 0.0f;

    const unsigned char* srcBase = reinterpret_cast<const unsigned char*>(bnb);

    // prologue: stage tile 0 into buffer 0 (swizzled: chunk c -> c ^ (row&7))
    {
        const unsigned char* src = srcBase + (size_t)jBase * 256;
#pragma unroll
        for (int it = 0; it < 4; ++it) {
            const int c  = it * 256 + tid;
            const int cd = c ^ ((c >> 4) & 7);
            *reinterpret_cast<uint4*>(lds + cd * 16) =
                *reinterpret_cast<const uint4*>(src + (size_t)c * 16);
        }
    }

    for (int jt = 0; jt < NT; ++jt) {
        __syncthreads();   // writes to buf[jt&1] visible; buf[(jt+1)&1] free

        const bool havenext = (jt + 1 < NT);
        uint4 vstage[4];
        if (havenext) {
            const unsigned char* src = srcBase + (size_t)(jBase + (jt + 1) * BN_TILE) * 256;
#pragma unroll
            for (int it = 0; it < 4; ++it)
                vstage[it] = *reinterpret_cast<const uint4*>(src + (size_t)(it * 256 + tid) * 16);
        }

        const unsigned char* ldsr = lds + (jt & 1) * TILE_BYTES;
#pragma unroll
        for (int jsub = 0; jsub < 4; ++jsub) {
            bf16x8 b[4];
            const int r = jsub * 16 + l15;   // tile row = output column j
#pragma unroll
            for (int kk = 0; kk < 4; ++kk) {
                const int cl = r * 16 + kk * 4 + l4;   // linear chunk
                const int ca = cl ^ (r & 7);           // swizzled
                b[kk] = *reinterpret_cast<const bf16x8*>(ldsr + ca * 16);
            }
#pragma unroll
            for (int s = 0; s < 4; ++s) {
                f32x4 acc = {0.0f, 0.0f, 0.0f, 0.0f};
#pragma unroll
                for (int kk = 0; kk < 4; ++kk)
                    acc = __builtin_amdgcn_mfma_f32_16x16x32_bf16(a[s][kk], b[kk], acc, 0, 0, 0);
#pragma unroll
                for (int e = 0; e < 4; ++e)
                    sums[s][e] += EXP2(fmaf(acc[e], SCALE, OFFSET));
            }
        }

        if (havenext) {
            unsigned char* ldsw = lds + ((jt + 1) & 1) * TILE_BYTES;
#pragma unroll
            for (int it = 0; it < 4; ++it) {
                const int c  = it * 256 + tid;
                const int cd = c ^ ((c >> 4) & 7);
                *reinterpret_cast<uint4*>(ldsw + cd * 16) = vstage[it];
            }
        }
    }

    // reduce each running sum over the 16 column-holding lanes (lane&15)
#pragma unroll
    for (int s = 0; s < 4; ++s)
#pragma unroll
        for (int e = 0; e < 4; ++e) {
            float v = sums[s][e];
            v += __shfl_xor(v, 1);
            v += __shfl_xor(v, 2);
            v += __shfl_xor(v, 4);
            v += __shfl_xor(v, 8);
            sums[s][e] = v;
        }
    if (l15 == 0) {
#pragma unroll
        for (int s = 0; s < 4; ++s)
#pragma unroll
            for (int e = 0; e < 4; ++e) {
                const int row = rowBase + s * 16 + l4 * 4 + e;
                partial[(size_t)row * NJ + blockIdx.y] = sums[s][e];
            }
    }
}

// ---------------------------------------------------------------------------
// Kernel 3: per-row merge + ln + diag subtract; per-block partial sums.
// grid = 32 blocks x 256 threads (one thread per row).
// ---------------------------------------------------------------------------
__global__ void finalize_rows_kernel(const float* __restrict__ partial,
                                     const float* __restrict__ diag,
                                     float* __restrict__ blocksum) {
    const int t = threadIdx.x;
    const int r = blockIdx.x * 256 + t;
    float se = 0.0f;
#pragma unroll
    for (int c = 0; c < NJ; ++c) se += partial[(size_t)r * NJ + c];
    float res = 20.0f + logf(se) - diag[r];
#pragma unroll
    for (int o = 32; o >= 1; o >>= 1) res += __shfl_xor(res, o);
    __shared__ float red[4];
    if ((t & 63) == 0) red[t >> 6] = res;
    __syncthreads();
    if (t == 0) blocksum[blockIdx.x] = red[0] + red[1] + red[2] + red[3];
}

// ---------------------------------------------------------------------------
// Kernel 4: final reduce of 32 block sums -> mean -> d_out[0].
// ---------------------------------------------------------------------------
__global__ void final_kernel(const float* __restrict__ blocksum,
                             float* __restrict__ out) {
    const int t = threadIdx.x;  // 64 threads
    float v = (t < 32) ? blocksum[t] : 0.0f;
#pragma unroll
    for (int o = 32; o >= 1; o >>= 1) v += __shfl_xor(v, o);
    if (t == 0) out[0] = v * (1.0f / (float)N_ROWS);
}

// ---------------------------------------------------------------------------
extern "C" void kernel_launch(void* const* d_in, const int* in_sizes, int n_in,
                              void* d_out, int out_size, void* d_ws, size_t ws_size,
                              hipStream_t stream) {
    const float* z   = (const float*)d_in[0];
    const float* zp  = (const float*)d_in[1];
    const float* znm = (const float*)d_in[2];

    char* ws = (char*)d_ws;
    // workspace layout (bytes):
    //   znb     : [8192][128] bf16            @ 0         (2,097,152)
    //   bnb     : [16384][128] bf16           @ 2,097,152 (4,194,304)
    //   diag    : [8192] f32                  @ 6,291,456 (32,768)
    //   partial : [8192][NJ=32] f32           @ 6,324,224 (1,048,576)
    //   blocksum: [32] f32                    @ 7,372,800 (128)
    __bf16* znb     = (__bf16*)(ws);
    __bf16* bnb     = (__bf16*)(ws + 2097152);
    float*  diag    = (float*)(ws + 6291456);
    float*  partial = (float*)(ws + 6324224);
    float*  blocksum= (float*)(ws + 7372800);
    float*  out     = (float*)d_out;

    normalize_diag_kernel<<<N_ROWS / 4, 256, 0, stream>>>(z, zp, znm, znb, bnb, diag);
    partial_lse_kernel<<<dim3(N_ROWS / BLOCK_ROWS, NJ), 256, 0, stream>>>(znb, bnb, partial);
    finalize_rows_kernel<<<N_ROWS / 256, 256, 0, stream>>>(partial, diag, blocksum);
    final_kernel<<<1, 64, 0, stream>>>(blocksum, out);
}

// Round 3
// 52.971 us; speedup vs baseline: 3.1330x; 3.1330x over previous
//
#include <hip/hip_runtime.h>
#include <hip/hip_bf16.h>
#include <stdint.h>

// ---------------------------------------------------------------------------
// SupervisedInfoNCELoss, N=8192, D=128, TAF=0.05
// loss = mean_i [ 20 + ln(sum_j exp(logit_ij - 20)) - diag_i ]
// logit_ij = zn_i . bn_j / TAF,  bn = [normalize(z_p); normalize(z_n)]
// Fixed max = 20 (cos sim <= 1) -> no online max needed.
// ---------------------------------------------------------------------------

#define TAF_F 0.05f
constexpr float LOG2E  = 1.4426950408889634f;
constexpr float SCALE  = LOG2E / TAF_F;     // logit->exp2 scale on raw dot
constexpr float OFFSET = -20.0f * LOG2E;    // subtract fixed max 20

constexpr int N_ROWS     = 8192;
constexpr int D_DIM      = 128;
constexpr int TWO_N      = 16384;
constexpr int NJ         = 32;              // column chunks (gridDim.y)
constexpr int JCHUNK     = TWO_N / NJ;      // 512 columns per block
constexpr int BN_TILE    = 64;              // j-tile staged in LDS
constexpr int NT         = JCHUNK / BN_TILE;// 8 tiles per block
constexpr int BLOCK_ROWS = 256;             // rows per block (4 waves x 64)
constexpr int WAVE_ROWS  = 64;              // rows per wave (4 strips of 16)
constexpr int TILE_BYTES = BN_TILE * D_DIM * 2;  // 16 KiB

typedef __bf16 bf16x8 __attribute__((ext_vector_type(8)));
typedef __bf16 bf16x2 __attribute__((ext_vector_type(2)));
typedef float  f32x4  __attribute__((ext_vector_type(4)));

typedef __attribute__((address_space(3))) uint32_t       lds_u32;
typedef const __attribute__((address_space(1))) uint32_t glb_u32;

#if __has_builtin(__builtin_amdgcn_exp2f)
#define EXP2(x) __builtin_amdgcn_exp2f(x)
#else
#define EXP2(x) exp2f(x)
#endif

// ---------------------------------------------------------------------------
// Kernel 1: per-row normalize -> bf16, plus exact f32 diagonal logit.
// One wave per row (lane holds 2 elems); 4 rows per 256-thread block.
// ---------------------------------------------------------------------------
__global__ void normalize_diag_kernel(const float* __restrict__ z,
                                      const float* __restrict__ zp,
                                      const float* __restrict__ znm,
                                      __bf16* __restrict__ znb,
                                      __bf16* __restrict__ bnb,
                                      float* __restrict__ diag) {
    const int wv   = threadIdx.x >> 6;
    const int lane = threadIdx.x & 63;
    const int i    = blockIdx.x * 4 + wv;

    const float2 vz = *reinterpret_cast<const float2*>(z   + (size_t)i * D_DIM + lane * 2);
    const float2 vp = *reinterpret_cast<const float2*>(zp  + (size_t)i * D_DIM + lane * 2);
    const float2 vn = *reinterpret_cast<const float2*>(znm + (size_t)i * D_DIM + lane * 2);

    float sz  = vz.x * vz.x + vz.y * vz.y;
    float sp  = vp.x * vp.x + vp.y * vp.y;
    float sn  = vn.x * vn.x + vn.y * vn.y;
    float szp = vz.x * vp.x + vz.y * vp.y;
#pragma unroll
    for (int o = 32; o >= 1; o >>= 1) {
        sz  += __shfl_xor(sz, o);
        sp  += __shfl_xor(sp, o);
        sn  += __shfl_xor(sn, o);
        szp += __shfl_xor(szp, o);
    }
    const float rz = 1.0f / fmaxf(sqrtf(sz), 1e-8f);
    const float rp = 1.0f / fmaxf(sqrtf(sp), 1e-8f);
    const float rn = 1.0f / fmaxf(sqrtf(sn), 1e-8f);

    bf16x2 oz = { (__bf16)(vz.x * rz), (__bf16)(vz.y * rz) };
    bf16x2 op = { (__bf16)(vp.x * rp), (__bf16)(vp.y * rp) };
    bf16x2 on = { (__bf16)(vn.x * rn), (__bf16)(vn.y * rn) };
    *reinterpret_cast<bf16x2*>(znb + (size_t)i * D_DIM + lane * 2)            = oz;
    *reinterpret_cast<bf16x2*>(bnb + (size_t)i * D_DIM + lane * 2)            = op;
    *reinterpret_cast<bf16x2*>(bnb + (size_t)(N_ROWS + i) * D_DIM + lane * 2) = on;
    if (lane == 0) diag[i] = szp * rz * rp * (1.0f / TAF_F);
}

// ---------------------------------------------------------------------------
// Kernel 2: fused GEMM + partial sum-of-exp. Double-buffered LDS staged via
// global_load_lds (width=16, linear LDS dest, XOR-swizzled global source).
// grid = (N/256, NJ=32) = 1024 blocks -> 4 blocks/CU (VGPR ~104 -> 4 w/SIMD).
// LDS[s] holds global chunk s ^ ((s>>4)&7)  (16B chunks, row = s>>4).
// mfma_f32_16x16x32_bf16: C row = (lane>>4)*4+reg, col = lane&15 (m89).
// ---------------------------------------------------------------------------
__global__ __launch_bounds__(256, 2) void partial_lse_kernel(
        const __bf16* __restrict__ znb,
        const __bf16* __restrict__ bnb,
        float* __restrict__ partial) {
    __shared__ __align__(16) unsigned char lds[TILE_BYTES * 2];  // 32 KiB

    const int tid  = threadIdx.x;
    const int lane = tid & 63;
    const int wv   = tid >> 6;
    const int l15  = lane & 15;
    const int l4   = lane >> 4;
    const int rowBase = blockIdx.x * BLOCK_ROWS + wv * WAVE_ROWS;
    const int jBase   = blockIdx.y * JCHUNK;

    const unsigned char* srcBase = reinterpret_cast<const unsigned char*>(bnb);

    // async stage: tile -> lds buffer (linear dest, pre-swizzled source)
    auto stage = [&](int tile, int buf) {
        const unsigned char* srcTile = srcBase + (size_t)(jBase + tile * BN_TILE) * 256;
        unsigned char* ldsw = lds + buf * TILE_BYTES;
#pragma unroll
        for (int it = 0; it < 4; ++it) {
            const int s = it * 256 + tid;          // linear 16B-chunk in LDS
            const int g = s ^ ((s >> 4) & 7);      // swizzled source chunk
            __builtin_amdgcn_global_load_lds(
                (glb_u32*)(srcTile + (size_t)g * 16),
                (lds_u32*)(ldsw + s * 16), 16, 0, 0);
        }
    };

    // A fragments for 4 row-strips x 4 K-steps (held in VGPRs whole kernel)
    bf16x8 a[4][4];
#pragma unroll
    for (int s = 0; s < 4; ++s)
#pragma unroll
        for (int kk = 0; kk < 4; ++kk) {
            const __bf16* p = znb + (size_t)(rowBase + s * 16 + l15) * D_DIM + kk * 32 + l4 * 8;
            a[s][kk] = *reinterpret_cast<const bf16x8*>(p);
        }

    float sums[4][4];
#pragma unroll
    for (int s = 0; s < 4; ++s)
#pragma unroll
        for (int e = 0; e < 4; ++e) sums[s][e] = 0.0f;

    stage(0, 0);   // prologue

    for (int jt = 0; jt < NT; ++jt) {
        __syncthreads();   // tile jt ready in buf[jt&1]; prev reads drained

        if (jt + 1 < NT) stage(jt + 1, (jt + 1) & 1);  // overlaps with compute

        const unsigned char* ldsr = lds + (jt & 1) * TILE_BYTES;
#pragma unroll
        for (int jsub = 0; jsub < 4; ++jsub) {
            bf16x8 b[4];
            const int r = jsub * 16 + l15;   // tile row = output column j
#pragma unroll
            for (int kk = 0; kk < 4; ++kk) {
                const int cl = r * 16 + kk * 4 + l4;   // linear chunk
                const int ca = cl ^ (r & 7);           // swizzled
                b[kk] = *reinterpret_cast<const bf16x8*>(ldsr + ca * 16);
            }
#pragma unroll
            for (int s = 0; s < 4; ++s) {
                f32x4 acc = {0.0f, 0.0f, 0.0f, 0.0f};
#pragma unroll
                for (int kk = 0; kk < 4; ++kk)
                    acc = __builtin_amdgcn_mfma_f32_16x16x32_bf16(a[s][kk], b[kk], acc, 0, 0, 0);
#pragma unroll
                for (int e = 0; e < 4; ++e)
                    sums[s][e] += EXP2(fmaf(acc[e], SCALE, OFFSET));
            }
        }
    }

    // reduce each running sum over the 16 column-holding lanes (lane&15)
#pragma unroll
    for (int s = 0; s < 4; ++s)
#pragma unroll
        for (int e = 0; e < 4; ++e) {
            float v = sums[s][e];
            v += __shfl_xor(v, 1);
            v += __shfl_xor(v, 2);
            v += __shfl_xor(v, 4);
            v += __shfl_xor(v, 8);
            sums[s][e] = v;
        }
    if (l15 == 0) {
#pragma unroll
        for (int s = 0; s < 4; ++s)
#pragma unroll
            for (int e = 0; e < 4; ++e) {
                const int row = rowBase + s * 16 + l4 * 4 + e;
                partial[(size_t)row * NJ + blockIdx.y] = sums[s][e];
            }
    }
}

// ---------------------------------------------------------------------------
// Kernel 3: per-row merge + ln + diag subtract; per-block partial sums.
// grid = 32 blocks x 256 threads (one thread per row), float4 loads.
// ---------------------------------------------------------------------------
__global__ void finalize_rows_kernel(const float* __restrict__ partial,
                                     const float* __restrict__ diag,
                                     float* __restrict__ blocksum) {
    const int t = threadIdx.x;
    const int r = blockIdx.x * 256 + t;
    const float4* prow = reinterpret_cast<const float4*>(partial + (size_t)r * NJ);
    float se = 0.0f;
#pragma unroll
    for (int c = 0; c < NJ / 4; ++c) {
        const float4 v = prow[c];
        se += (v.x + v.y) + (v.z + v.w);
    }
    float res = 20.0f + logf(se) - diag[r];
#pragma unroll
    for (int o = 32; o >= 1; o >>= 1) res += __shfl_xor(res, o);
    __shared__ float red[4];
    if ((t & 63) == 0) red[t >> 6] = res;
    __syncthreads();
    if (t == 0) blocksum[blockIdx.x] = red[0] + red[1] + red[2] + red[3];
}

// ---------------------------------------------------------------------------
// Kernel 4: final reduce of 32 block sums -> mean -> d_out[0].
// ---------------------------------------------------------------------------
__global__ void final_kernel(const float* __restrict__ blocksum,
                             float* __restrict__ out) {
    const int t = threadIdx.x;  // 64 threads
    float v = (t < 32) ? blocksum[t] : 0.0f;
#pragma unroll
    for (int o = 32; o >= 1; o >>= 1) v += __shfl_xor(v, o);
    if (t == 0) out[0] = v * (1.0f / (float)N_ROWS);
}

// ---------------------------------------------------------------------------
extern "C" void kernel_launch(void* const* d_in, const int* in_sizes, int n_in,
                              void* d_out, int out_size, void* d_ws, size_t ws_size,
                              hipStream_t stream) {
    const float* z   = (const float*)d_in[0];
    const float* zp  = (const float*)d_in[1];
    const float* znm = (const float*)d_in[2];

    char* ws = (char*)d_ws;
    // workspace layout (bytes):
    //   znb     : [8192][128] bf16            @ 0         (2,097,152)
    //   bnb     : [16384][128] bf16           @ 2,097,152 (4,194,304)
    //   diag    : [8192] f32                  @ 6,291,456 (32,768)
    //   partial : [8192][NJ=32] f32           @ 6,324,224 (1,048,576)
    //   blocksum: [32] f32                    @ 7,372,800 (128)
    __bf16* znb     = (__bf16*)(ws);
    __bf16* bnb     = (__bf16*)(ws + 2097152);
    float*  diag    = (float*)(ws + 6291456);
    float*  partial = (float*)(ws + 6324224);
    float*  blocksum= (float*)(ws + 7372800);
    float*  out     = (float*)d_out;

    normalize_diag_kernel<<<N_ROWS / 4, 256, 0, stream>>>(z, zp, znm, znb, bnb, diag);
    partial_lse_kernel<<<dim3(N_ROWS / BLOCK_ROWS, NJ), 256, 0, stream>>>(znb, bnb, partial);
    finalize_rows_kernel<<<N_ROWS / 256, 256, 0, stream>>>(partial, diag, blocksum);
    final_kernel<<<1, 64, 0, stream>>>(blocksum, out);
}